// Round 3
// baseline (273.406 us; speedup 1.0000x reference)
//
#include <hip/hip_runtime.h>
#include <stdint.h>

#define BATCH 128
#define NN 512
#define BINS 100
#define WORDS 8    // 512 bits / 64; natural order: bit b of word m = column 64m+b
#define WPAD 9     // +1 u64 pad -> benign LDS bank aliasing
#define ECAP 6144  // upper-tri edge capacity; expected ~2615, huge margin

// spread 16 bits to stride-4 positions (bit i -> bit 4i)
__device__ __forceinline__ unsigned long long spread4(unsigned long long x) {
    x = (x | (x << 24)) & 0x000000ff000000ffull;
    x = (x | (x << 12)) & 0x000f000f000f000full;
    x = (x | (x <<  6)) & 0x0303030303030303ull;
    x = (x | (x <<  3)) & 0x1111111111111111ull;
    return x;
}

// R10 (3rd submit; rounds 1-2 hit GPUAcquisitionTimeout, never ran): split
// the latency-bound float->bit pack out of the per-graph kernel. R9's
// phase-1 was pinned at ~30 cyc/line/CU (1 block/CU, 16 waves, ~1
// outstanding dependent load each -> ~3-5x below per-CU HBM share).
// k_pack runs 196,608 independent waves (32 waves/CU, no LDS) so the same
// ~151 MB upper-span read is BW-bound (~24 us), writing 8.4 MB of packed
// bitmaps that k_tri_hist re-reads from L2/L3 in ~32 KB/graph.

// One wave per item (graph g, row r, 256-col half h). Half h covers words
// 4h..4h+3; first needed word within the half is ws (diagonal-block clip).
// The diagonal word is read in FULL (A is exactly symmetric, zero diag, so
// below-diagonal bits are true values) -> diagonal 64x64 blocks need no
// completion pass; only off-diagonal transposes remain in k_tri_hist.
// Items per graph: 512 rows * (h=1 always) + 256 rows (br<=3) * (h=0) = 768.
#define PACK_WAVES (2 * BATCH * 768)
#define PACK_BLOCKS (PACK_WAVES / 16)  // 12288 blocks of 1024 threads

__global__ __launch_bounds__(1024) void k_pack(
    const float* __restrict__ adj1, const float* __restrict__ adj2,
    unsigned long long* __restrict__ ub /* [2*BATCH][NN][WORDS] */)
{
    const int wv   = blockIdx.x * 16 + (threadIdx.x >> 6);
    const int lane = threadIdx.x & 63;
    const int g    = wv / 768;
    const int rem  = wv - g * 768;
    const int h    = rem < NN ? 1 : 0;                // words 4h..4h+3
    const int r    = h ? rem : rem - NN;              // h==0 only for r<256
    const int br   = r >> 6;                          // diagonal 64-col block
    const int ws   = h ? (br > 4 ? br - 4 : 0) : br;  // first needed word in half

    const float* __restrict__ gp =
        (g < BATCH ? adj1 : adj2) + (size_t)(g & (BATCH - 1)) * NN * NN;

    float4 v = make_float4(0.f, 0.f, 0.f, 0.f);
    if (lane >= 16 * ws)
        v = *(const float4*)(gp + (size_t)r * NN + (h << 8) + 4 * lane);
    unsigned long long b0 = __ballot(v.x != 0.0f);
    unsigned long long b1 = __ballot(v.y != 0.0f);
    unsigned long long b2 = __ballot(v.z != 0.0f);
    unsigned long long b3 = __ballot(v.w != 0.0f);
    // lane d in [ws,4) assembles word 4h+d from ballot bits 16d..16d+15
    if (lane >= ws && lane < 4) {
        const int sh = 16 * lane;                     // < 64 always
        unsigned long long w =
            (spread4((b0 >> sh) & 0xFFFFull) << 0) |
            (spread4((b1 >> sh) & 0xFFFFull) << 1) |
            (spread4((b2 >> sh) & 0xFFFFull) << 2) |
            (spread4((b3 >> sh) & 0xFFFFull) << 3);
        ub[((size_t)(g * NN + r) << 3) + (h << 2) + lane] = w;
    }
}

// Per-graph kernel: load packed bits (32 KB), rebuild lower triangle by 28
// off-diagonal 64x64 bit transposes, then edge list / intersection counts /
// clustering histogram exactly as in R9.
__global__ __launch_bounds__(1024) void k_tri_hist(
    const unsigned long long* __restrict__ ub,
    float* __restrict__ hist /* [2*BATCH][BINS] */)
{
    __shared__ unsigned long long bits[NN][WPAD];   // 36,864 B
    __shared__ unsigned int edges[ECAP];            // 24,576 B
    __shared__ int tri2[NN];                        //  2,048 B
    __shared__ int histI[BINS];
    __shared__ int ecnt;

    const int gb   = blockIdx.x;  // 0..255
    const int tid  = threadIdx.x;
    const int lane = tid & 63;
    const int wave = tid >> 6;    // 0..15

    if (tid < BINS) histI[tid] = 0;
    if (tid < NN)   tri2[tid]  = 0;
    if (tid == 0)   ecnt = 0;

    // ---- Phase A: packed bits -> LDS (coalesced u64). Words m < br hold
    // poison from the workspace re-fill; phase 1b overwrites all of them
    // before any use (it only READS upper words m=bi > bj=row-block).
    const unsigned long long* __restrict__ gsrc = ub + ((size_t)gb << 12);
    for (int p = tid; p < NN * WORDS; p += 1024)
        bits[p >> 3][p & 7] = gsrc[p];
    __syncthreads();

    // ---- Phase 1b: lower triangle by symmetry: 28 off-diagonal pairs
    // (bi,bj), bj<bi. Diagonal blocks arrived complete from k_pack.
    for (int p = wave; p < 28; p += 16) {
        int bi = 1;
        while (bi * (bi + 1) / 2 <= p) ++bi;
        int bj = p - bi * (bi - 1) / 2;
        unsigned long long t = bits[(bj << 6) + lane][bi];
        const unsigned long long M[6] = {
            0x5555555555555555ull, 0x3333333333333333ull,
            0x0f0f0f0f0f0f0f0full, 0x00ff00ff00ff00ffull,
            0x0000ffff0000ffffull, 0x00000000ffffffffull };
        #pragma unroll
        for (int s = 0; s < 6; ++s) {
            const int k = 1 << s;
            unsigned long long y = __shfl_xor((long long)t, k, 64);
            if ((lane & k) == 0) t = (t &  M[s]) | ((y &  M[s]) << k);
            else                 t = (t & ~M[s]) | ((y & ~M[s]) >> k);
        }
        bits[(bi << 6) + lane][bj] = t;
    }
    __syncthreads();

    // ---- Phase 2a: upper-tri edge list (j > r); j = 64m + L.
    for (int p = tid; p < NN * WORDS; p += 1024) {
        int r = p >> 3;
        int m = p & 7;
        unsigned long long w = bits[r][m];
        int base = m << 6;
        int sh = r - base + 1;  // keep bits L with base+L > r
        unsigned long long wm =
            (sh <= 0) ? w : (sh >= 64 ? 0ull : (w & (~0ull << sh)));
        int cnt = __popcll(wm);

        int x = cnt;
        #pragma unroll
        for (int off = 1; off < 64; off <<= 1) {
            int y = __shfl_up(x, off, 64);
            if (lane >= off) x += y;
        }
        int excl = x - cnt;
        int bs = 0;
        if (lane == 63) bs = atomicAdd(&ecnt, x);
        bs = __shfl(bs, 63, 64);

        int idx = bs + excl;
        while (wm) {
            int L = __builtin_ctzll(wm);
            wm &= wm - 1;
            int j = base + L;
            if (idx < ECAP) edges[idx] = ((unsigned)r << 10) | (unsigned)j;
            ++idx;
        }
    }
    __syncthreads();

    // ---- Phase 2b: edge-parallel intersection counts.
    const int ne = ecnt < ECAP ? ecnt : ECAP;
    for (int e = tid; e < ne; e += 1024) {
        unsigned ed = edges[e];
        int i = ed >> 10;
        int j = ed & 1023;
        int acc = 0;
        #pragma unroll
        for (int w = 0; w < WORDS; ++w)
            acc += __popcll(bits[i][w] & bits[j][w]);
        atomicAdd(&tri2[i], acc);
        atomicAdd(&tri2[j], acc);
    }
    __syncthreads();

    // ---- Phase 2c: clustering coeff + histogram.
    if (tid < NN) {
        int deg = 0;
        #pragma unroll
        for (int w = 0; w < WORDS; ++w) deg += __popcll(bits[tid][w]);
        float t2    = (float)tri2[tid];
        float degf  = (float)deg;
        float denom = degf * (degf - 1.0f);
        float c = denom > 0.0f ? t2 / denom : 0.0f;  // exact int/int in fp32
        int idx = (int)(c * 100.0f);                  // trunc == astype(int32)
        idx = idx < 0 ? 0 : (idx > BINS - 1 ? BINS - 1 : idx);
        atomicAdd(&histI[idx], 1);
    }
    __syncthreads();

    if (tid < BINS) hist[(size_t)gb * BINS + tid] = (float)histI[tid];
}

// ---------------- MMD kernels ----------------------------------------------
__global__ __launch_bounds__(256) void k_mmd_partial(
    const float* __restrict__ hist, float* __restrict__ partials)
{
    int p = blockIdx.x * 256 + threadIdx.x;
    int t   = p >> 14;          // 0:XX 1:YY 2:XY
    int rem = p & 16383;
    int i = rem >> 7;
    int j = rem & 127;
    const float4* x4;
    const float4* y4;
    float w;
    if (t == 0)      { x4 = (const float4*)(hist + (size_t)i * BINS);           y4 = (const float4*)(hist + (size_t)j * BINS);           w =  1.0f; }
    else if (t == 1) { x4 = (const float4*)(hist + (size_t)(BATCH + i) * BINS); y4 = (const float4*)(hist + (size_t)(BATCH + j) * BINS); w =  1.0f; }
    else             { x4 = (const float4*)(hist + (size_t)i * BINS);           y4 = (const float4*)(hist + (size_t)(BATCH + j) * BINS); w = -2.0f; }
    float sq = 0.0f;
    #pragma unroll
    for (int k = 0; k < BINS / 4; ++k) {
        float4 a = x4[k];
        float4 b = y4[k];
        float d0 = a.x - b.x, d1 = a.y - b.y, d2 = a.z - b.z, d3 = a.w - b.w;
        sq += d0 * d0 + d1 * d1 + d2 * d2 + d3 * d3;
    }
    float local = w * expf(-0.5f * sq);  // sigma=1

    __shared__ float red[256];
    red[threadIdx.x] = local;
    __syncthreads();
    for (int s = 128; s >= 1; s >>= 1) {
        if (threadIdx.x < s) red[threadIdx.x] += red[threadIdx.x + s];
        __syncthreads();
    }
    if (threadIdx.x == 0) partials[blockIdx.x] = red[0];
}

__global__ __launch_bounds__(64) void k_mmd_final(
    const float* __restrict__ partials, float* __restrict__ out, int nparts)
{
    int lane = threadIdx.x;
    float v = 0.0f;
    for (int p = lane; p < nparts; p += 64) v += partials[p];
    #pragma unroll
    for (int off = 32; off >= 1; off >>= 1) v += __shfl_xor(v, off, 64);
    if (lane == 0) out[0] = v * (1.0f / (float)(BATCH * BATCH));
}

extern "C" void kernel_launch(void* const* d_in, const int* in_sizes, int n_in,
                              void* d_out, int out_size, void* d_ws, size_t ws_size,
                              hipStream_t stream) {
    const float* a1 = (const float*)d_in[0];
    const float* a2 = (const float*)d_in[1];
    float* out = (float*)d_out;

    const size_t hist_bytes = (size_t)2 * BATCH * BINS * 4;  // 102,400 B
    float* hist     = (float*)d_ws;
    float* partials = (float*)((char*)d_ws + hist_bytes);
    // packed bitmaps: 2*BATCH * 512 rows * 8 u64 = 8,388,608 B
    unsigned long long* ub =
        (unsigned long long*)((char*)d_ws + 103424);  // 256B-aligned offset

    hipLaunchKernelGGL(k_pack, dim3(PACK_BLOCKS), dim3(1024), 0, stream,
                       a1, a2, ub);
    hipLaunchKernelGGL(k_tri_hist, dim3(2 * BATCH), dim3(1024), 0, stream,
                       ub, hist);
    hipLaunchKernelGGL(k_mmd_partial, dim3(192), dim3(256), 0, stream,
                       hist, partials);
    hipLaunchKernelGGL(k_mmd_final, dim3(1), dim3(64), 0, stream,
                       partials, out, 192);
}

// Round 5
// 262.961 us; speedup vs baseline: 1.0397x; 1.0397x over previous
//
#include <hip/hip_runtime.h>
#include <stdint.h>

#define BATCH 128
#define NN 512
#define BINS 100
#define WORDS 8    // 512 bits / 64; natural order: bit b of word m = column 64m+b
#define WPAD 9     // +1 u64 pad -> benign LDS bank aliasing
#define ECAP 6144  // upper-tri edge capacity; expected ~2615, huge margin

// spread 16 bits to stride-4 positions (bit i -> bit 4i)
__device__ __forceinline__ unsigned long long spread4(unsigned long long x) {
    x = (x | (x << 24)) & 0x000000ff000000ffull;
    x = (x | (x << 12)) & 0x000f000f000f000full;
    x = (x | (x <<  6)) & 0x0303030303030303ull;
    x = (x | (x <<  3)) & 0x1111111111111111ull;
    return x;
}

// R11 (2nd submit; round 4 hit GPUAcquisitionTimeout, never ran): revert
// R10's two-kernel split (273us: extra launch + 8.4MB round-trip lost to
// R9's 258us monolith). Keep the monolith; fix phase-1's memory-level
// parallelism IN PLACE: R9 issued 1 masked float4 load per wave then
// immediately balloted it (~16KB in flight/CU). Now each wave loads 8 rows'
// float4s back-to-back (independent; compiler waits vmcnt(7) before the
// first ballot) -> ~64KB in flight/CU, same traffic, no extra kernel.
// Also fuse k_mmd_final into k_mmd_partial (last-block pattern) to drop one
// dispatch boundary. Numerics bit-identical to R9 (same reduction order).
__global__ __launch_bounds__(1024) void k_cluster_hist(
    const float* __restrict__ adj1, const float* __restrict__ adj2,
    float* __restrict__ hist /* [2*BATCH][BINS] */,
    unsigned int* __restrict__ mmd_cnt)
{
    __shared__ unsigned long long bits[NN][WPAD];   // 36,864 B
    __shared__ unsigned int edges[ECAP];            // 24,576 B
    __shared__ int tri2[NN];                        //  2,048 B
    __shared__ int histI[BINS];
    __shared__ int ecnt;

    const int gb = blockIdx.x;  // 0..255
    const float* __restrict__ gp =
        (gb < BATCH ? adj1 : adj2) + (size_t)(gb & (BATCH - 1)) * NN * NN;

    const int tid  = threadIdx.x;
    const int lane = tid & 63;
    const int wave = tid >> 6;  // 0..15

    if (tid < BINS) histI[tid] = 0;
    if (tid < NN)   tri2[tid]  = 0;
    if (tid == 0)   ecnt = 0;
    if (gb == 0 && tid == 0) *mmd_cnt = 0;  // arm the fused-MMD last-block flag

    // ---- Phase 1: upper-triangle read + natural-order pack, 8 rows/wave in
    // flight. Wave w covers rows w+16k, k=0..31; unroll k by 8 so all 8
    // global_load_dwordx4 issue before the first dependent __ballot.
    for (int k0 = 0; k0 < 32; k0 += 8) {
        float4 v[8];
        #pragma unroll
        for (int q = 0; q < 8; ++q) {
            const int r  = wave + ((k0 + q) << 4);
            const int br = r >> 6;       // diagonal 64-col block
            const int nb = 8 - br;       // words to read
            const int c0 = br << 6;
            const int rr = r & 63;
            // lanes 0..15 cover the diagonal word; skip lanes w/ all 4 cols <= r
            const int Lmin = (rr < 3) ? 0 : ((rr + 1) >> 2);
            v[q] = make_float4(0.f, 0.f, 0.f, 0.f);
            if (lane < 16 * nb && (lane >= 16 || lane >= Lmin))
                v[q] = *(const float4*)(gp + (size_t)r * NN + c0 + 4 * lane);
        }
        #pragma unroll
        for (int q = 0; q < 8; ++q) {
            const int r  = wave + ((k0 + q) << 4);
            const int br = r >> 6;
            const int nb = 8 - br;
            unsigned long long b0 = __ballot(v[q].x != 0.0f);
            unsigned long long b1 = __ballot(v[q].y != 0.0f);
            unsigned long long b2 = __ballot(v[q].z != 0.0f);
            unsigned long long b3 = __ballot(v[q].w != 0.0f);
            // lane d < nb assembles natural word m = br + d from span word s = d
            if (lane < nb) {
                const int sh = 16 * lane;
                unsigned long long w =
                    (spread4((b0 >> sh) & 0xFFFFull) << 0) |
                    (spread4((b1 >> sh) & 0xFFFFull) << 1) |
                    (spread4((b2 >> sh) & 0xFFFFull) << 2) |
                    (spread4((b3 >> sh) & 0xFFFFull) << 3);
                bits[r][br + lane] = w;
            }
        }
    }
    __syncthreads();

    // ---- Phase 1b: fill lower triangle by symmetry (64x64 bit transposes).
    // Items 0..27: off-diagonal pairs (bi,bj), bj<bi. Items 28..35: diagonal
    // blocks bi=bj=p-28, completed as x | transpose(x).
    for (int p = wave; p < 36; p += 16) {
        int bi, bj;
        if (p < 28) {
            bi = 1;
            while (bi * (bi + 1) / 2 <= p) ++bi;
            bj = p - bi * (bi - 1) / 2;
        } else {
            bi = p - 28; bj = bi;
        }
        unsigned long long x = bits[(bj << 6) + lane][bi];
        unsigned long long t = x;
        const unsigned long long M[6] = {
            0x5555555555555555ull, 0x3333333333333333ull,
            0x0f0f0f0f0f0f0f0full, 0x00ff00ff00ff00ffull,
            0x0000ffff0000ffffull, 0x00000000ffffffffull };
        #pragma unroll
        for (int s = 0; s < 6; ++s) {
            const int k = 1 << s;
            unsigned long long y = __shfl_xor((long long)t, k, 64);
            if ((lane & k) == 0) t = (t &  M[s]) | ((y &  M[s]) << k);
            else                 t = (t & ~M[s]) | ((y & ~M[s]) >> k);
        }
        if (p < 28) bits[(bi << 6) + lane][bj] = t;       // pure transpose
        else        bits[(bi << 6) + lane][bi] = x | t;   // symmetric completion
    }
    __syncthreads();

    // ---- Phase 2a: upper-tri edge list (j > r); j = 64m + L.
    for (int p = tid; p < NN * WORDS; p += 1024) {
        int r = p >> 3;
        int m = p & 7;
        unsigned long long w = bits[r][m];
        int base = m << 6;
        int sh = r - base + 1;  // keep bits L with base+L > r
        unsigned long long wm =
            (sh <= 0) ? w : (sh >= 64 ? 0ull : (w & (~0ull << sh)));
        int cnt = __popcll(wm);

        int x = cnt;
        #pragma unroll
        for (int off = 1; off < 64; off <<= 1) {
            int y = __shfl_up(x, off, 64);
            if (lane >= off) x += y;
        }
        int excl = x - cnt;
        int bs = 0;
        if (lane == 63) bs = atomicAdd(&ecnt, x);
        bs = __shfl(bs, 63, 64);

        int idx = bs + excl;
        while (wm) {
            int L = __builtin_ctzll(wm);
            wm &= wm - 1;
            int j = base + L;
            if (idx < ECAP) edges[idx] = ((unsigned)r << 10) | (unsigned)j;
            ++idx;
        }
    }
    __syncthreads();

    // ---- Phase 2b: edge-parallel intersection counts.
    const int ne = ecnt < ECAP ? ecnt : ECAP;
    for (int e = tid; e < ne; e += 1024) {
        unsigned ed = edges[e];
        int i = ed >> 10;
        int j = ed & 1023;
        int acc = 0;
        #pragma unroll
        for (int w = 0; w < WORDS; ++w)
            acc += __popcll(bits[i][w] & bits[j][w]);
        atomicAdd(&tri2[i], acc);
        atomicAdd(&tri2[j], acc);
    }
    __syncthreads();

    // ---- Phase 2c: clustering coeff + histogram.
    if (tid < NN) {
        int deg = 0;
        #pragma unroll
        for (int w = 0; w < WORDS; ++w) deg += __popcll(bits[tid][w]);
        float t2    = (float)tri2[tid];
        float degf  = (float)deg;
        float denom = degf * (degf - 1.0f);
        float c = denom > 0.0f ? t2 / denom : 0.0f;  // exact int/int in fp32
        int idx = (int)(c * 100.0f);                  // trunc == astype(int32)
        idx = idx < 0 ? 0 : (idx > BINS - 1 ? BINS - 1 : idx);
        atomicAdd(&histI[idx], 1);
    }
    __syncthreads();

    if (tid < BINS) hist[(size_t)gb * BINS + tid] = (float)histI[tid];
}

// ---------------- fused MMD kernel (partial + last-block final) -------------
__global__ __launch_bounds__(256) void k_mmd(
    const float* __restrict__ hist, float* __restrict__ partials,
    unsigned int* __restrict__ cnt, float* __restrict__ out)
{
    int p = blockIdx.x * 256 + threadIdx.x;
    int t   = p >> 14;          // 0:XX 1:YY 2:XY
    int rem = p & 16383;
    int i = rem >> 7;
    int j = rem & 127;
    const float4* x4;
    const float4* y4;
    float w;
    if (t == 0)      { x4 = (const float4*)(hist + (size_t)i * BINS);           y4 = (const float4*)(hist + (size_t)j * BINS);           w =  1.0f; }
    else if (t == 1) { x4 = (const float4*)(hist + (size_t)(BATCH + i) * BINS); y4 = (const float4*)(hist + (size_t)(BATCH + j) * BINS); w =  1.0f; }
    else             { x4 = (const float4*)(hist + (size_t)i * BINS);           y4 = (const float4*)(hist + (size_t)(BATCH + j) * BINS); w = -2.0f; }
    float sq = 0.0f;
    #pragma unroll
    for (int k = 0; k < BINS / 4; ++k) {
        float4 a = x4[k];
        float4 b = y4[k];
        float d0 = a.x - b.x, d1 = a.y - b.y, d2 = a.z - b.z, d3 = a.w - b.w;
        sq += d0 * d0 + d1 * d1 + d2 * d2 + d3 * d3;
    }
    float local = w * expf(-0.5f * sq);  // sigma=1

    __shared__ float red[256];
    __shared__ bool amLast;
    red[threadIdx.x] = local;
    __syncthreads();
    for (int s = 128; s >= 1; s >>= 1) {
        if (threadIdx.x < s) red[threadIdx.x] += red[threadIdx.x + s];
        __syncthreads();
    }
    if (threadIdx.x == 0) {
        partials[blockIdx.x] = red[0];
        __threadfence();                        // release partial (device scope)
        amLast = (atomicAdd(cnt, 1u) == 191u);  // device-scope counter
    }
    __syncthreads();
    if (amLast) {
        __threadfence();                        // acquire others' partials
        if (threadIdx.x < 64) {
            // byte-identical reduction order to R9's k_mmd_final
            float v = 0.0f;
            for (int q = threadIdx.x; q < 192; q += 64) v += partials[q];
            #pragma unroll
            for (int off = 32; off >= 1; off >>= 1) v += __shfl_xor(v, off, 64);
            if (threadIdx.x == 0) out[0] = v * (1.0f / (float)(BATCH * BATCH));
        }
    }
}

extern "C" void kernel_launch(void* const* d_in, const int* in_sizes, int n_in,
                              void* d_out, int out_size, void* d_ws, size_t ws_size,
                              hipStream_t stream) {
    const float* a1 = (const float*)d_in[0];
    const float* a2 = (const float*)d_in[1];
    float* out = (float*)d_out;

    const size_t hist_bytes = (size_t)2 * BATCH * BINS * 4;  // 102,400 B
    float* hist            = (float*)d_ws;
    float* partials        = (float*)((char*)d_ws + hist_bytes);          // 768 B
    unsigned int* mmd_cnt  = (unsigned int*)((char*)d_ws + hist_bytes + 1024);

    hipLaunchKernelGGL(k_cluster_hist, dim3(2 * BATCH), dim3(1024), 0, stream,
                       a1, a2, hist, mmd_cnt);
    hipLaunchKernelGGL(k_mmd, dim3(192), dim3(256), 0, stream,
                       hist, partials, mmd_cnt, out);
}

// Round 6
// 261.168 us; speedup vs baseline: 1.0469x; 1.0069x over previous
//
#include <hip/hip_runtime.h>
#include <stdint.h>

#define BATCH 128
#define NN 512
#define BINS 100
#define WORDS 8    // 512 bits / 64; natural order: bit b of word m = column 64m+b
#define WPAD 9     // +1 u64 pad -> benign LDS bank aliasing
#define ECAP 6144  // upper-tri edge capacity; expected ~2615, huge margin

// spread 16 bits to stride-4 positions (bit i -> bit 4i)
__device__ __forceinline__ unsigned long long spread4(unsigned long long x) {
    x = (x | (x << 24)) & 0x000000ff000000ffull;
    x = (x | (x << 12)) & 0x000f000f000f000full;
    x = (x | (x <<  6)) & 0x0303030303030303ull;
    x = (x | (x <<  3)) & 0x1111111111111111ull;
    return x;
}

// R12: channel-phase-decorrelation experiment.
// Evidence so far: phase-1 pinned ~30cyc/line/CU across 5 prior structures,
// R10's fully wave-parallel split (273us), and R11's 8-deep MLP unroll
// (263us) -> the pin is NOT latency/MLP. Common factor: graphs are 1MiB
// apart and all 256 blocks walk rows in the SAME order simultaneously ->
// identical low-20 address bits machine-wide -> all CUs hammer the same
// HBM channel subset at once. Fix: per-block row-phase rotation
// (r = (wave+16k+rot)&511, rot=gb*73&511). Zero traffic/instruction change;
// pure address-stream decorrelation. Phase-1 is row-order independent.
// Also: revert R11's 8-row unroll (measured +5us) to R9's 1-row loop; keep
// R11's fused last-block MMD (saves one dispatch boundary).
__global__ __launch_bounds__(1024) void k_cluster_hist(
    const float* __restrict__ adj1, const float* __restrict__ adj2,
    float* __restrict__ hist /* [2*BATCH][BINS] */,
    unsigned int* __restrict__ mmd_cnt)
{
    __shared__ unsigned long long bits[NN][WPAD];   // 36,864 B
    __shared__ unsigned int edges[ECAP];            // 24,576 B
    __shared__ int tri2[NN];                        //  2,048 B
    __shared__ int histI[BINS];
    __shared__ int ecnt;

    const int gb = blockIdx.x;  // 0..255
    const float* __restrict__ gp =
        (gb < BATCH ? adj1 : adj2) + (size_t)(gb & (BATCH - 1)) * NN * NN;

    const int tid  = threadIdx.x;
    const int lane = tid & 63;
    const int wave = tid >> 6;  // 0..15

    if (tid < BINS) histI[tid] = 0;
    if (tid < NN)   tri2[tid]  = 0;
    if (tid == 0)   ecnt = 0;
    if (gb == 0 && tid == 0) *mmd_cnt = 0;  // arm the fused-MMD last-block flag

    // ---- Phase 1: upper-triangle read + natural-order pack, R9 form, with
    // per-block row-phase rotation to decorrelate HBM channel access.
    const int rot = (gb * 73) & (NN - 1);  // 256 distinct phases (73 odd)
    for (int k = 0; k < 32; ++k) {
        const int r  = (wave + (k << 4) + rot) & (NN - 1);
        const int br = r >> 6;       // diagonal 64-col block
        const int nb = 8 - br;       // words to read
        const int c0 = br << 6;
        const int rr = r & 63;
        // lanes 0..15 cover the diagonal word; skip lanes w/ all 4 cols <= r
        const int Lmin = (rr < 3) ? 0 : ((rr + 1) >> 2);
        float4 v = make_float4(0.f, 0.f, 0.f, 0.f);
        if (lane < 16 * nb && (lane >= 16 || lane >= Lmin))
            v = *(const float4*)(gp + (size_t)r * NN + c0 + 4 * lane);
        unsigned long long b0 = __ballot(v.x != 0.0f);
        unsigned long long b1 = __ballot(v.y != 0.0f);
        unsigned long long b2 = __ballot(v.z != 0.0f);
        unsigned long long b3 = __ballot(v.w != 0.0f);
        // lane d < nb assembles natural word m = br + d from span word s = d
        if (lane < nb) {
            const int sh = 16 * lane;
            unsigned long long w =
                (spread4((b0 >> sh) & 0xFFFFull) << 0) |
                (spread4((b1 >> sh) & 0xFFFFull) << 1) |
                (spread4((b2 >> sh) & 0xFFFFull) << 2) |
                (spread4((b3 >> sh) & 0xFFFFull) << 3);
            bits[r][br + lane] = w;
        }
    }
    __syncthreads();

    // ---- Phase 1b: fill lower triangle by symmetry (64x64 bit transposes).
    // Items 0..27: off-diagonal pairs (bi,bj), bj<bi. Items 28..35: diagonal
    // blocks bi=bj=p-28, completed as x | transpose(x).
    for (int p = wave; p < 36; p += 16) {
        int bi, bj;
        if (p < 28) {
            bi = 1;
            while (bi * (bi + 1) / 2 <= p) ++bi;
            bj = p - bi * (bi - 1) / 2;
        } else {
            bi = p - 28; bj = bi;
        }
        unsigned long long x = bits[(bj << 6) + lane][bi];
        unsigned long long t = x;
        const unsigned long long M[6] = {
            0x5555555555555555ull, 0x3333333333333333ull,
            0x0f0f0f0f0f0f0f0full, 0x00ff00ff00ff00ffull,
            0x0000ffff0000ffffull, 0x00000000ffffffffull };
        #pragma unroll
        for (int s = 0; s < 6; ++s) {
            const int k = 1 << s;
            unsigned long long y = __shfl_xor((long long)t, k, 64);
            if ((lane & k) == 0) t = (t &  M[s]) | ((y &  M[s]) << k);
            else                 t = (t & ~M[s]) | ((y & ~M[s]) >> k);
        }
        if (p < 28) bits[(bi << 6) + lane][bj] = t;       // pure transpose
        else        bits[(bi << 6) + lane][bi] = x | t;   // symmetric completion
    }
    __syncthreads();

    // ---- Phase 2a: upper-tri edge list (j > r); j = 64m + L.
    for (int p = tid; p < NN * WORDS; p += 1024) {
        int r = p >> 3;
        int m = p & 7;
        unsigned long long w = bits[r][m];
        int base = m << 6;
        int sh = r - base + 1;  // keep bits L with base+L > r
        unsigned long long wm =
            (sh <= 0) ? w : (sh >= 64 ? 0ull : (w & (~0ull << sh)));
        int cnt = __popcll(wm);

        int x = cnt;
        #pragma unroll
        for (int off = 1; off < 64; off <<= 1) {
            int y = __shfl_up(x, off, 64);
            if (lane >= off) x += y;
        }
        int excl = x - cnt;
        int bs = 0;
        if (lane == 63) bs = atomicAdd(&ecnt, x);
        bs = __shfl(bs, 63, 64);

        int idx = bs + excl;
        while (wm) {
            int L = __builtin_ctzll(wm);
            wm &= wm - 1;
            int j = base + L;
            if (idx < ECAP) edges[idx] = ((unsigned)r << 10) | (unsigned)j;
            ++idx;
        }
    }
    __syncthreads();

    // ---- Phase 2b: edge-parallel intersection counts.
    const int ne = ecnt < ECAP ? ecnt : ECAP;
    for (int e = tid; e < ne; e += 1024) {
        unsigned ed = edges[e];
        int i = ed >> 10;
        int j = ed & 1023;
        int acc = 0;
        #pragma unroll
        for (int w = 0; w < WORDS; ++w)
            acc += __popcll(bits[i][w] & bits[j][w]);
        atomicAdd(&tri2[i], acc);
        atomicAdd(&tri2[j], acc);
    }
    __syncthreads();

    // ---- Phase 2c: clustering coeff + histogram.
    if (tid < NN) {
        int deg = 0;
        #pragma unroll
        for (int w = 0; w < WORDS; ++w) deg += __popcll(bits[tid][w]);
        float t2    = (float)tri2[tid];
        float degf  = (float)deg;
        float denom = degf * (degf - 1.0f);
        float c = denom > 0.0f ? t2 / denom : 0.0f;  // exact int/int in fp32
        int idx = (int)(c * 100.0f);                  // trunc == astype(int32)
        idx = idx < 0 ? 0 : (idx > BINS - 1 ? BINS - 1 : idx);
        atomicAdd(&histI[idx], 1);
    }
    __syncthreads();

    if (tid < BINS) hist[(size_t)gb * BINS + tid] = (float)histI[tid];
}

// ---------------- fused MMD kernel (partial + last-block final) -------------
__global__ __launch_bounds__(256) void k_mmd(
    const float* __restrict__ hist, float* __restrict__ partials,
    unsigned int* __restrict__ cnt, float* __restrict__ out)
{
    int p = blockIdx.x * 256 + threadIdx.x;
    int t   = p >> 14;          // 0:XX 1:YY 2:XY
    int rem = p & 16383;
    int i = rem >> 7;
    int j = rem & 127;
    const float4* x4;
    const float4* y4;
    float w;
    if (t == 0)      { x4 = (const float4*)(hist + (size_t)i * BINS);           y4 = (const float4*)(hist + (size_t)j * BINS);           w =  1.0f; }
    else if (t == 1) { x4 = (const float4*)(hist + (size_t)(BATCH + i) * BINS); y4 = (const float4*)(hist + (size_t)(BATCH + j) * BINS); w =  1.0f; }
    else             { x4 = (const float4*)(hist + (size_t)i * BINS);           y4 = (const float4*)(hist + (size_t)(BATCH + j) * BINS); w = -2.0f; }
    float sq = 0.0f;
    #pragma unroll
    for (int k = 0; k < BINS / 4; ++k) {
        float4 a = x4[k];
        float4 b = y4[k];
        float d0 = a.x - b.x, d1 = a.y - b.y, d2 = a.z - b.z, d3 = a.w - b.w;
        sq += d0 * d0 + d1 * d1 + d2 * d2 + d3 * d3;
    }
    float local = w * expf(-0.5f * sq);  // sigma=1

    __shared__ float red[256];
    __shared__ bool amLast;
    red[threadIdx.x] = local;
    __syncthreads();
    for (int s = 128; s >= 1; s >>= 1) {
        if (threadIdx.x < s) red[threadIdx.x] += red[threadIdx.x + s];
        __syncthreads();
    }
    if (threadIdx.x == 0) {
        partials[blockIdx.x] = red[0];
        __threadfence();                        // release partial (device scope)
        amLast = (atomicAdd(cnt, 1u) == 191u);  // device-scope counter
    }
    __syncthreads();
    if (amLast) {
        __threadfence();                        // acquire others' partials
        if (threadIdx.x < 64) {
            // byte-identical reduction order to R9's k_mmd_final
            float v = 0.0f;
            for (int q = threadIdx.x; q < 192; q += 64) v += partials[q];
            #pragma unroll
            for (int off = 32; off >= 1; off >>= 1) v += __shfl_xor(v, off, 64);
            if (threadIdx.x == 0) out[0] = v * (1.0f / (float)(BATCH * BATCH));
        }
    }
}

extern "C" void kernel_launch(void* const* d_in, const int* in_sizes, int n_in,
                              void* d_out, int out_size, void* d_ws, size_t ws_size,
                              hipStream_t stream) {
    const float* a1 = (const float*)d_in[0];
    const float* a2 = (const float*)d_in[1];
    float* out = (float*)d_out;

    const size_t hist_bytes = (size_t)2 * BATCH * BINS * 4;  // 102,400 B
    float* hist            = (float*)d_ws;
    float* partials        = (float*)((char*)d_ws + hist_bytes);          // 768 B
    unsigned int* mmd_cnt  = (unsigned int*)((char*)d_ws + hist_bytes + 1024);

    hipLaunchKernelGGL(k_cluster_hist, dim3(2 * BATCH), dim3(1024), 0, stream,
                       a1, a2, hist, mmd_cnt);
    hipLaunchKernelGGL(k_mmd, dim3(192), dim3(256), 0, stream,
                       hist, partials, mmd_cnt, out);
}